// Round 8
// baseline (538.934 us; speedup 1.0000x reference)
//
#include <hip/hip_runtime.h>
#include <hip/hip_bf16.h>

#define B_  8
#define D_  256
#define N_  8192
#define M_  8192
#define O1_ 512     // 2D
#define K1_ 768     // 3D
#define K2_ 512     // 2D

typedef unsigned short u16;
typedef __attribute__((ext_vector_type(8))) short bf8;   // 8 bf16 = 4 VGPRs
typedef __attribute__((ext_vector_type(4))) float f4;

static __device__ __forceinline__ float bf2f(u16 u) {
    unsigned v = ((unsigned)u) << 16;
    return __uint_as_float(v);
}
static __device__ __forceinline__ u16 f2bf(float f) {
    __hip_bfloat16 h = __float2bfloat16(f);
    return *reinterpret_cast<u16*>(&h);
}
// async global->LDS, 16B per lane; LDS dest = wave-uniform base + lane*16
static __device__ __forceinline__ void gl_lds16(const u16* g, u16* l) {
    __builtin_amdgcn_global_load_lds((const __attribute__((address_space(1))) void*)g,
                                     (__attribute__((address_space(3))) void*)l, 16, 0, 0);
}
// byte-offset swizzle within a 64B LDS row: spreads 16 same-slot rows across banks
static __device__ __forceinline__ int swz64(int r) {
    return (((r >> 1) & 1) << 4) | (((r >> 2) & 1) << 5);
}

// ---------------- transpose f32 [B][R][C] -> bf16 [B][C][R] (64x64 tiles, 128B stores) ----------------
__global__ __launch_bounds__(256) void k_transpose_bf16(const float* __restrict__ src,
                                                        u16* __restrict__ dst, int R, int C) {
    __shared__ float t[64][65];
    const int b  = blockIdx.z;
    const int c0 = blockIdx.x * 64, r0 = blockIdx.y * 64;
    const int tx = threadIdx.x, ty = threadIdx.y;     // block (64,4)
    const float* s = src + (size_t)b * R * C;
    u16* d = dst + (size_t)b * C * R;
#pragma unroll
    for (int i = 0; i < 16; ++i) {
        int r = r0 + ty + i * 4;
        t[ty + i * 4][tx] = s[(size_t)r * C + (c0 + tx)];
    }
    __syncthreads();
#pragma unroll
    for (int i = 0; i < 16; ++i) {
        int c = c0 + ty + i * 4;
        d[(size_t)c * R + (r0 + tx)] = f2bf(t[tx][ty + i * 4]);
    }
}

// ---------------- weights f32 -> bf16 ----------------
__global__ __launch_bounds__(256) void k_convert_w(const float* __restrict__ W1, const float* __restrict__ W2,
                                                   u16* __restrict__ W1b, u16* __restrict__ W2b) {
    int i = blockIdx.x * 256 + threadIdx.x;
    const int n1 = O1_ * K1_;
    const int n2 = D_ * K2_;
    if (i < n1) W1b[i] = f2bf(W1[i]);
    int j = i - n1;
    if (j >= 0 && j < n2) W2b[j] = f2bf(W2[j]);
}

// ---------------- GEMM1 (128x128 tile, 4 waves, BK=32, ring-3 LDS, counted vmcnt, swizzled) ----------------
// h'[b][m][o] = W1 @ msg ; msg k-segments: [0,256) Tld[idx[m]], [256,512) Tld[idx[m^1]], [512,768) Tle[m]
#define NT1 24    // K1/32
__global__ __launch_bounds__(256, 3) void k_gemm1(const u16* __restrict__ W1b,
                                                  const u16* __restrict__ Tld,
                                                  const u16* __restrict__ Tle,
                                                  const int* __restrict__ idx,
                                                  u16* __restrict__ hbuf) {
    __shared__ u16 LA[3][128 * 32];   // 3 x 8KB
    __shared__ u16 LB[3][128 * 32];   // 3 x 8KB
    const int b  = blockIdx.z;
    const int o0 = blockIdx.y * 128;
    const int m0 = blockIdx.x * 128;
    const int tid = threadIdx.x;
    const int w = tid >> 6, l = tid & 63;
    const int wr = w >> 1, wc = w & 1;

    // staging: load j covers row j*64 + (tid>>2), 16B chunk (tid&3)*16 within 64B row
    const int srow   = tid >> 2;          // 0..63
    const int scol16 = (tid & 3) * 16;    // byte col

    int na[2], nb[2], mm[2];
    const u16* aSrc[2];
    int bcol[2];
#pragma unroll
    for (int j = 0; j < 2; ++j) {
        int r = j * 64 + srow;
        int m = m0 + r;
        mm[j] = m;
        na[j] = idx[b * M_ + m];
        nb[j] = idx[b * M_ + (m ^ 1)];
        int sw = swz64(r);
        aSrc[j] = W1b + (size_t)(o0 + r) * K1_ + ((scol16 ^ sw) >> 1);
        bcol[j] = (scol16 ^ sw) >> 1;
    }

    // fragment read offsets (u16 index), swizzled to match staging permutation
    int ar[4], br[4];
#pragma unroll
    for (int i = 0; i < 4; ++i) {
        int r = wr * 64 + i * 16 + (l & 15);
        ar[i] = r * 32 + ((((l >> 4) * 16) ^ swz64(r)) >> 1);
    }
#pragma unroll
    for (int j = 0; j < 4; ++j) {
        int r = wc * 64 + j * 16 + (l & 15);
        br[j] = r * 32 + ((((l >> 4) * 16) ^ swz64(r)) >> 1);
    }

#define STAGE1(kt, buf)                                                                 \
    {                                                                                   \
        const int seg = (kt) >> 3;                                                      \
        const int off = ((kt) & 7) * 32;                                                \
        _Pragma("unroll")                                                               \
        for (int j = 0; j < 2; ++j)                                                     \
            gl_lds16(aSrc[j] + (kt) * 32, &LA[buf][j * 2048 + tid * 8]);                \
        _Pragma("unroll")                                                               \
        for (int j = 0; j < 2; ++j) {                                                   \
            const u16* s;                                                               \
            if (seg == 0)      s = Tld + (size_t)(b * N_ + na[j]) * D_ + off + bcol[j]; \
            else if (seg == 1) s = Tld + (size_t)(b * N_ + nb[j]) * D_ + off + bcol[j]; \
            else               s = Tle + (size_t)(b * M_ + mm[j]) * D_ + off + bcol[j]; \
            gl_lds16(s, &LB[buf][j * 2048 + tid * 8]);                                  \
        }                                                                               \
    }

    f4 acc[4][4];
#pragma unroll
    for (int i = 0; i < 4; ++i)
#pragma unroll
        for (int j = 0; j < 4; ++j) acc[i][j] = {0.f, 0.f, 0.f, 0.f};

    // prologue: tiles 0,1 in flight (8 loads); wait tile 0 (oldest 4)
    STAGE1(0, 0);
    STAGE1(1, 1);
    asm volatile("s_waitcnt vmcnt(4)" ::: "memory");
    __builtin_amdgcn_s_barrier();
    __builtin_amdgcn_sched_barrier(0);

    for (int t = 0; t < NT1; ++t) {
        const int buf = t % 3;
        if (t + 2 < NT1) STAGE1(t + 2, (t + 2) % 3);   // slot (t+2)%3 == (t-1)%3: consumed

        bf8 aF[4], bF[4];
#pragma unroll
        for (int i = 0; i < 4; ++i) aF[i] = *reinterpret_cast<const bf8*>(&LA[buf][ar[i]]);
#pragma unroll
        for (int j = 0; j < 4; ++j) bF[j] = *reinterpret_cast<const bf8*>(&LB[buf][br[j]]);

        __builtin_amdgcn_s_setprio(1);
#pragma unroll
        for (int i = 0; i < 4; ++i)
#pragma unroll
            for (int j = 0; j < 4; ++j)
                acc[i][j] = __builtin_amdgcn_mfma_f32_16x16x32_bf16(aF[i], bF[j], acc[i][j], 0, 0, 0);
        __builtin_amdgcn_s_setprio(0);

        // counted drain: tile t+1 (oldest 4) must be landed; t+2 stays in flight
        if (t < NT1 - 2) asm volatile("s_waitcnt vmcnt(4)" ::: "memory");
        else             asm volatile("s_waitcnt vmcnt(0)" ::: "memory");
        __builtin_amdgcn_s_barrier();
        __builtin_amdgcn_sched_barrier(0);
    }
#undef STAGE1

    // epilogue: store bf16 h' to hbuf[b][m][o] (o fast)
#pragma unroll
    for (int j = 0; j < 4; ++j) {
        int m = m0 + wc * 64 + j * 16 + (l & 15);
        size_t rowbase = (size_t)(b * M_ + m) * O1_;
#pragma unroll
        for (int i = 0; i < 4; ++i) {
            int orow = o0 + wr * 64 + i * 16 + (l >> 4) * 4;
            ushort4 pk;
            pk.x = f2bf(acc[i][j].x);
            pk.y = f2bf(acc[i][j].y);
            pk.z = f2bf(acc[i][j].z);
            pk.w = f2bf(acc[i][j].w);
            *reinterpret_cast<ushort4*>(&hbuf[rowbase + orow]) = pk;
        }
    }
}

// ---------------- per-channel sum / sumsq over h' (2048 blocks for TLP) ----------------
__global__ __launch_bounds__(256) void k_stats(const u16* __restrict__ hbuf, float* __restrict__ stats) {
    const int t = threadIdx.x;
    const size_t row0 = (size_t)blockIdx.x * 32;
    float s0 = 0.f, q0 = 0.f, s1 = 0.f, q1 = 0.f;
    for (int r = 0; r < 32; ++r) {
        const u16* p = hbuf + (row0 + r) * O1_;
        float v0 = bf2f(p[t]);
        float v1 = bf2f(p[t + 256]);
        s0 += v0; q0 += v0 * v0;
        s1 += v1; q1 += v1 * v1;
    }
    atomicAdd(&stats[t], s0);
    atomicAdd(&stats[O1_ + t], q0);
    atomicAdd(&stats[t + 256], s1);
    atomicAdd(&stats[O1_ + t + 256], q1);
}

__global__ void k_finalize_ac(const float* __restrict__ stats, const float* __restrict__ g1,
                              const float* __restrict__ bt1, float* __restrict__ ac) {
    int o = blockIdx.x * 256 + threadIdx.x;
    if (o >= O1_) return;
    const float inv = 1.0f / ((float)B_ * (float)M_);
    float mean = stats[o] * inv;
    float var  = stats[O1_ + o] * inv - mean * mean;
    var = fmaxf(var, 0.0f);
    float a = g1[o] * rsqrtf(var + 1e-5f);
    ac[o] = a;
    ac[O1_ + o] = bt1[o] - mean * a;   // b1 cancels: shift = bt1 - a*mean(h')
}

// ---------------- CSR build: count -> scan -> fill ----------------
__global__ void k_count_int(const int* __restrict__ idx, int* __restrict__ cnt) {
    int i = blockIdx.x * 256 + threadIdx.x;
    if (i < B_ * M_) atomicAdd(&cnt[(i >> 13) * N_ + idx[i]], 1);
}

__global__ __launch_bounds__(1024) void k_scan(const int* __restrict__ cnt, int* __restrict__ offs,
                                               int* __restrict__ fill) {
    __shared__ int wsum[1024];
    const int b = blockIdx.x;
    const int t = threadIdx.x;
    const int base = b * N_;
    int v[8]; int s = 0;
#pragma unroll
    for (int k = 0; k < 8; ++k) { v[k] = cnt[base + t * 8 + k]; s += v[k]; }
    wsum[t] = s;
    __syncthreads();
    for (int off = 1; off < 1024; off <<= 1) {
        int add = (t >= off) ? wsum[t - off] : 0;
        __syncthreads();
        wsum[t] += add;
        __syncthreads();
    }
    int run = (t > 0) ? wsum[t - 1] : 0;
#pragma unroll
    for (int k = 0; k < 8; ++k) {
        offs[base + t * 8 + k] = run;
        fill[base + t * 8 + k] = run;
        run += v[k];
    }
}

__global__ void k_fill(const int* __restrict__ idx, int* __restrict__ fill, int* __restrict__ mlist) {
    int i = blockIdx.x * 256 + threadIdx.x;
    if (i < B_ * M_) {
        int b = i >> 13, m = i & (M_ - 1);
        int pos = atomicAdd(&fill[b * N_ + idx[i]], 1);
        mlist[(size_t)b * M_ + pos] = m;
    }
}

// ---------------- GEMM2: up[b][m][d] = W2 @ relu(a*h'+c) + b2 (BN+ReLU fused into B-staging) ----------------
__global__ __launch_bounds__(256) void k_gemm2(const u16* __restrict__ W2b,
                                               const u16* __restrict__ hbuf,
                                               const float* __restrict__ ac,
                                               const float* __restrict__ b2,
                                               u16* __restrict__ up) {
    __shared__ u16 At[128 * 32];
    __shared__ u16 Bt[128 * 32];
    __shared__ float acs[1024];    // [0,512) scale a, [512,1024) shift c
    const int b  = blockIdx.z;
    const int d0 = blockIdx.y * 128;
    const int m0 = blockIdx.x * 128;
    const int tid = threadIdx.x;
    const int w = tid >> 6, l = tid & 63;
    const int lr = l >> 2, lc = (l & 3) * 8;

    acs[tid]       = ac[tid];
    acs[tid + 256] = ac[tid + 256];
    acs[tid + 512] = ac[tid + 512];
    acs[tid + 768] = ac[tid + 768];

    const u16* pA[2]; const u16* pB[2];
#pragma unroll
    for (int t = 0; t < 2; ++t) {
        int row = t * 64 + w * 16 + lr;
        pA[t] = W2b + (size_t)(d0 + row) * K2_ + lc;
        int m  = m0 + row;
        pB[t] = hbuf + (size_t)(b * M_ + m) * O1_ + lc;
    }
    const int wr = w >> 1, wc = w & 1;
    f4 acc[4][4];
#pragma unroll
    for (int i = 0; i < 4; ++i)
#pragma unroll
        for (int j = 0; j < 4; ++j) acc[i][j] = {0.f, 0.f, 0.f, 0.f};

    const int aoff = (wr * 64 + (l & 15)) * 32 + (l >> 4) * 8;
    const int boff = (wc * 64 + (l & 15)) * 32 + (l >> 4) * 8;
    const int bdst = (w * 16 + lr) * 32 + lc;   // +t*64*32 per chunk

    __syncthreads();   // acs visible before first transform

    for (int kk = 0; kk < 16; ++kk) {
        const int o = kk * 32 + lc;
        f4 A0 = *reinterpret_cast<const f4*>(&acs[o]);
        f4 A1 = *reinterpret_cast<const f4*>(&acs[o + 4]);
        f4 C0 = *reinterpret_cast<const f4*>(&acs[512 + o]);
        f4 C1 = *reinterpret_cast<const f4*>(&acs[512 + o + 4]);
#pragma unroll
        for (int t = 0; t < 2; ++t) {
            gl_lds16(pA[t] + kk * 32, At + (t * 64 + w * 16) * 32);
            const ushort4* ps = reinterpret_cast<const ushort4*>(pB[t] + kk * 32);
            ushort4 v0 = ps[0], v1 = ps[1];
            union { ushort4 u4[2]; bf8 v8; } pk;
            pk.u4[0].x = f2bf(fmaxf(bf2f(v0.x) * A0.x + C0.x, 0.0f));
            pk.u4[0].y = f2bf(fmaxf(bf2f(v0.y) * A0.y + C0.y, 0.0f));
            pk.u4[0].z = f2bf(fmaxf(bf2f(v0.z) * A0.z + C0.z, 0.0f));
            pk.u4[0].w = f2bf(fmaxf(bf2f(v0.w) * A0.w + C0.w, 0.0f));
            pk.u4[1].x = f2bf(fmaxf(bf2f(v1.x) * A1.x + C1.x, 0.0f));
            pk.u4[1].y = f2bf(fmaxf(bf2f(v1.y) * A1.y + C1.y, 0.0f));
            pk.u4[1].z = f2bf(fmaxf(bf2f(v1.z) * A1.z + C1.z, 0.0f));
            pk.u4[1].w = f2bf(fmaxf(bf2f(v1.w) * A1.w + C1.w, 0.0f));
            *reinterpret_cast<bf8*>(&Bt[t * 64 * 32 + bdst]) = pk.v8;
        }
        __syncthreads();
        bf8 aF[4], bF[4];
#pragma unroll
        for (int i = 0; i < 4; ++i) aF[i] = *reinterpret_cast<const bf8*>(&At[aoff + i * 16 * 32]);
#pragma unroll
        for (int j = 0; j < 4; ++j) bF[j] = *reinterpret_cast<const bf8*>(&Bt[boff + j * 16 * 32]);
#pragma unroll
        for (int i = 0; i < 4; ++i)
#pragma unroll
            for (int j = 0; j < 4; ++j)
                acc[i][j] = __builtin_amdgcn_mfma_f32_16x16x32_bf16(aF[i], bF[j], acc[i][j], 0, 0, 0);
        __syncthreads();
    }

    // epilogue: +b2, plain bf16 stores to up[b][m][d]
#pragma unroll
    for (int j = 0; j < 4; ++j) {
        int m = m0 + wc * 64 + j * 16 + (l & 15);
        size_t rowbase = (size_t)(b * M_ + m) * D_;
#pragma unroll
        for (int i = 0; i < 4; ++i) {
            int d = d0 + wr * 64 + i * 16 + (l >> 4) * 4;
            ushort4 pk;
            pk.x = f2bf(acc[i][j].x + b2[d + 0]);
            pk.y = f2bf(acc[i][j].y + b2[d + 1]);
            pk.z = f2bf(acc[i][j].z + b2[d + 2]);
            pk.w = f2bf(acc[i][j].w + b2[d + 3]);
            *reinterpret_cast<ushort4*>(&up[rowbase + d]) = pk;
        }
    }
}

// ---------------- out[b][d][n] = ldesc + mean_{m in list(n)} up[b][m][d] ----------------
__global__ __launch_bounds__(256) void k_reduce_finalize(const float* __restrict__ ldesc,
                                                         const u16* __restrict__ up,
                                                         const int* __restrict__ cnt,
                                                         const int* __restrict__ offs,
                                                         const int* __restrict__ mlist,
                                                         float* __restrict__ out) {
    __shared__ float lds[32][257];
    const int b  = blockIdx.z;
    const int n0 = blockIdx.x * 32;
    const int tx = threadIdx.x, ty = threadIdx.y;   // (32,8)
#pragma unroll
    for (int i = 0; i < 4; ++i) {
        int nl = ty + i * 8;
        int n  = n0 + nl;
        int c   = cnt[b * N_ + n];
        int off = offs[b * N_ + n];
        float inv = 1.0f / (float)max(c, 1);
        float acc[8] = {0.f, 0.f, 0.f, 0.f, 0.f, 0.f, 0.f, 0.f};
        for (int e = 0; e < c; ++e) {
            int m = mlist[(size_t)b * M_ + off + e];
            const ushort4* row = reinterpret_cast<const ushort4*>(up + (size_t)(b * M_ + m) * D_ + tx * 8);
            ushort4 aa = row[0], bb = row[1];
            acc[0] += bf2f(aa.x); acc[1] += bf2f(aa.y); acc[2] += bf2f(aa.z); acc[3] += bf2f(aa.w);
            acc[4] += bf2f(bb.x); acc[5] += bf2f(bb.y); acc[6] += bf2f(bb.z); acc[7] += bf2f(bb.w);
        }
#pragma unroll
        for (int k = 0; k < 8; ++k) lds[nl][tx * 8 + k] = acc[k] * inv;
    }
    __syncthreads();
#pragma unroll
    for (int i = 0; i < 32; ++i) {
        int d = ty + i * 8;
        size_t o2 = (size_t)(b * D_ + d) * N_ + n0 + tx;
        out[o2] = ldesc[o2] + lds[tx][d];
    }
}

__global__ void k_marker(float* out, float v) { out[0] = v; }

extern "C" void kernel_launch(void* const* d_in, const int* in_sizes, int n_in,
                              void* d_out, int out_size, void* d_ws, size_t ws_size,
                              hipStream_t stream) {
    const float* ldesc0 = (const float*)d_in[0];
    const float* ldesc1 = (const float*)d_in[1];
    const float* le0    = (const float*)d_in[2];
    const float* le1    = (const float*)d_in[3];
    const int*   idx0   = (const int*)d_in[4];
    const int*   idx1   = (const int*)d_in[5];
    const float* W1     = (const float*)d_in[6];
    const float* g1     = (const float*)d_in[8];
    const float* bt1    = (const float*)d_in[9];
    const float* W2     = (const float*)d_in[10];
    const float* b2     = (const float*)d_in[11];
    float* out = (float*)d_out;

    char* ws = (char*)d_ws;
    const size_t oTld   = 0;                            // bf16 [B][N][D] 33.5MB; aliased by `up` after gemm1
    const size_t oTle   = 33554432;                     // bf16 [B][M][D] 33.5MB; aliased by CSR after gemm1
    const size_t oH     = 67108864;                     // bf16 [B][M][O1] 67MB
    const size_t oW1b   = 134217728;                    // 786,432 B
    const size_t oW2b   = oW1b + 786432;                // 262,144 B
    const size_t oStats = oW2b + 262144;                // 4,096 B
    const size_t oAC    = oStats + 4096;                // 4,096 B
    const size_t NEED   = oAC + 4096;
    if (ws_size < NEED) {
        k_marker<<<1, 1, 0, stream>>>(out, 1000.0f + (float)(ws_size >> 20));
        return;
    }
    u16*   Tld   = (u16*)(ws + oTld);
    u16*   up    = (u16*)(ws + oTld);                   // alias (Tld dead after gemm1)
    u16*   Tle   = (u16*)(ws + oTle);
    int*   cnt   = (int*)(ws + oTle);                   // CSR aliases Tle (dead after gemm1)
    int*   offs  = (int*)(ws + oTle + 262144);
    int*   fill  = (int*)(ws + oTle + 524288);
    int*   mlist = (int*)(ws + oTle + 786432);
    u16*   hbuf  = (u16*)(ws + oH);
    u16*   W1b   = (u16*)(ws + oW1b);
    u16*   W2b   = (u16*)(ws + oW2b);
    float* stats = (float*)(ws + oStats);
    float* ac    = (float*)(ws + oAC);

    k_convert_w<<<2048, 256, 0, stream>>>(W1, W2, W1b, W2b);

    const dim3 tb64(64, 4);
    const dim3 tb(32, 8);
    for (int s = 0; s < 2; ++s) {
        const float* ld  = s ? ldesc1 : ldesc0;
        const float* le  = s ? le1 : le0;
        const int*   idx = s ? idx1 : idx0;
        float* outp = out + (size_t)s * B_ * D_ * N_;

        k_transpose_bf16<<<dim3(N_ / 64, D_ / 64, B_), tb64, 0, stream>>>(ld, Tld, D_, N_);
        k_transpose_bf16<<<dim3(M_ / 64, D_ / 64, B_), tb64, 0, stream>>>(le, Tle, D_, M_);
        k_gemm1<<<dim3(M_ / 128, O1_ / 128, B_), 256, 0, stream>>>(W1b, Tld, Tle, idx, hbuf);
        // BN stats (streaming) + coefficients
        hipMemsetAsync(stats, 0, 4096, stream);
        k_stats<<<B_ * M_ / 32, 256, 0, stream>>>(hbuf, stats);
        k_finalize_ac<<<2, 256, 0, stream>>>(stats, g1, bt1, ac);
        // CSR of idx (Tle region is dead now)
        hipMemsetAsync(cnt, 0, (size_t)B_ * N_ * 4, stream);
        k_count_int<<<B_ * M_ / 256, 256, 0, stream>>>(idx, cnt);
        k_scan<<<B_, 1024, 0, stream>>>(cnt, offs, fill);
        k_fill<<<B_ * M_ / 256, 256, 0, stream>>>(idx, fill, mlist);
        // GEMM2 (fused BN+ReLU) -> up (Tld region is dead now), then gather-mean + residual
        k_gemm2<<<dim3(M_ / 128, D_ / 128, B_), 256, 0, stream>>>(W2b, hbuf, ac, b2, up);
        k_reduce_finalize<<<dim3(N_ / 32, 1, B_), tb, 0, stream>>>(ld, up, cnt, offs, mlist, outp);
    }
}

// Round 9
// 453.378 us; speedup vs baseline: 1.1887x; 1.1887x over previous
//
#include <hip/hip_runtime.h>
#include <hip/hip_bf16.h>

#define B_  8
#define D_  256
#define N_  8192
#define M_  8192
#define O1_ 512     // 2D
#define K1_ 768     // 3D
#define K2_ 512     // 2D

typedef unsigned short u16;
typedef __attribute__((ext_vector_type(8))) short bf8;   // 8 bf16 = 4 VGPRs
typedef __attribute__((ext_vector_type(4))) float f4;

static __device__ __forceinline__ float bf2f(u16 u) {
    unsigned v = ((unsigned)u) << 16;
    return __uint_as_float(v);
}
static __device__ __forceinline__ u16 f2bf(float f) {
    __hip_bfloat16 h = __float2bfloat16(f);
    return *reinterpret_cast<u16*>(&h);
}
// async global->LDS, 16B per lane; LDS dest = wave-uniform base + lane*16
static __device__ __forceinline__ void gl_lds16(const u16* g, u16* l) {
    __builtin_amdgcn_global_load_lds((const __attribute__((address_space(1))) void*)g,
                                     (__attribute__((address_space(3))) void*)l, 16, 0, 0);
}
// byte-offset swizzle within a 64B LDS row (bits 4,5 from row bits 1,2) — 0 conflicts (R8-verified)
static __device__ __forceinline__ int swz64(int r) {
    return (((r >> 1) & 1) << 4) | (((r >> 2) & 1) << 5);
}

// ---------------- transpose f32 [B][R][C] -> bf16 [B][C][R] (R6 version) ----------------
__global__ __launch_bounds__(256) void k_transpose_bf16(const float* __restrict__ src,
                                                        u16* __restrict__ dst, int R, int C) {
    __shared__ float t[32][33];
    const int b  = blockIdx.z;
    const int c0 = blockIdx.x * 32, r0 = blockIdx.y * 32;
    const int tx = threadIdx.x, ty = threadIdx.y;     // block (32,8)
    const float* s = src + (size_t)b * R * C;
    u16* d = dst + (size_t)b * C * R;
#pragma unroll
    for (int i = 0; i < 4; ++i) {
        int r = r0 + ty + i * 8;
        t[ty + i * 8][tx] = s[(size_t)r * C + (c0 + tx)];
    }
    __syncthreads();
#pragma unroll
    for (int i = 0; i < 4; ++i) {
        int c = c0 + ty + i * 8;
        d[(size_t)c * R + (r0 + tx)] = f2bf(t[tx][ty + i * 8]);
    }
}

// ---------------- weights f32 -> bf16 ----------------
__global__ __launch_bounds__(256) void k_convert_w(const float* __restrict__ W1, const float* __restrict__ W2,
                                                   u16* __restrict__ W1b, u16* __restrict__ W2b) {
    int i = blockIdx.x * 256 + threadIdx.x;
    const int n1 = O1_ * K1_;
    const int n2 = D_ * K2_;
    if (i < n1) W1b[i] = f2bf(W1[i]);
    int j = i - n1;
    if (j >= 0 && j < n2) W2b[j] = f2bf(W2[j]);
}

// ---------------- GEMM1: 256x256 tile, 8 waves, BK=64 (2 ks-planes), 8-phase dbuf, counted vmcnt ----------------
// h'[b][m][o] = W1 @ msg ; msg k-segments (256 wide = 4 K-tiles each):
//   kt 0-3: Tld[idx[m]] ; kt 4-7: Tld[idx[m^1]] ; kt 8-11: Tle[m]
#define NT1 12    // K1/64
__global__ __launch_bounds__(512, 2) void k_gemm1(const u16* __restrict__ W1b,
                                                  const u16* __restrict__ Tld,
                                                  const u16* __restrict__ Tle,
                                                  const int* __restrict__ idx,
                                                  u16* __restrict__ hbuf) {
    __shared__ u16 LA[2][2][256][32];   // [buf][ks][row o][32 u16 = 64B] : 64 KB
    __shared__ u16 LB[2][2][256][32];   // [buf][ks][row m][...]          : 64 KB
    const int b  = blockIdx.z;
    const int o0 = blockIdx.y * 256;
    const int m0 = blockIdx.x * 256;
    const int tid = threadIdx.x;
    const int w = tid >> 6, l = tid & 63;
    const int wr = w >> 2;      // o half: 128 rows
    const int wc = w & 3;       // m quarter: 64 rows

    // ---- staging geometry: sweep j covers row j*128 + (tid>>2), 16B chunk (tid&3) of 64B row ----
    const int srow   = tid >> 2;          // 0..127
    const int schunk = (tid & 3) * 16;    // byte offset in 64B row

    int na[2], nb[2], mm[2];
    const u16* aS[2];
    int bcolu[2];
#pragma unroll
    for (int j = 0; j < 2; ++j) {
        int r = j * 128 + srow;
        int m = m0 + r;
        mm[j] = m;
        na[j] = idx[b * M_ + m];
        nb[j] = idx[b * M_ + (m ^ 1)];
        int swu = (schunk ^ swz64(r)) >> 1;          // pre-swizzled source chunk (u16)
        aS[j]   = W1b + (size_t)(o0 + r) * K1_ + swu;
        bcolu[j] = swu;
    }

    // ---- fragment read offsets (u16 index within a [256][32] plane), swizzled ----
    int aOff[8], bOff[4];
#pragma unroll
    for (int i = 0; i < 8; ++i) {
        int r = wr * 128 + i * 16 + (l & 15);
        aOff[i] = r * 32 + ((((l >> 4) * 16) ^ swz64(r)) >> 1);
    }
#pragma unroll
    for (int j = 0; j < 4; ++j) {
        int r = wc * 64 + j * 16 + (l & 15);
        bOff[j] = r * 32 + ((((l >> 4) * 16) ^ swz64(r)) >> 1);
    }

#define STAGE_A1(kt, ks, buf)                                                        \
    {                                                                                \
        _Pragma("unroll")                                                            \
        for (int j = 0; j < 2; ++j)                                                  \
            gl_lds16(aS[j] + (kt) * 64 + (ks) * 32, &LA[buf][ks][j * 128][0] + tid * 8); \
    }
#define STAGE_B1(kt, ks, buf)                                                        \
    {                                                                                \
        const int seg = (kt) >> 2;                                                   \
        const int cb  = ((kt) & 3) * 64 + (ks) * 32;                                 \
        _Pragma("unroll")                                                            \
        for (int j = 0; j < 2; ++j) {                                                \
            const u16* s;                                                            \
            if (seg == 0)      s = Tld + (size_t)(b * N_ + na[j]) * D_ + cb + bcolu[j]; \
            else if (seg == 1) s = Tld + (size_t)(b * N_ + nb[j]) * D_ + cb + bcolu[j]; \
            else               s = Tle + (size_t)(b * M_ + mm[j]) * D_ + cb + bcolu[j]; \
            gl_lds16(s, &LB[buf][ks][j * 128][0] + tid * 8);                         \
        }                                                                            \
    }

    f4 acc[8][4];
#pragma unroll
    for (int i = 0; i < 8; ++i)
#pragma unroll
        for (int j = 0; j < 4; ++j) acc[i][j] = {0.f, 0.f, 0.f, 0.f};

    // ---- prologue: t0 all 4 planes + t1 ks0 planes (12 loads); force t0 ks0 (oldest 4) ----
    STAGE_A1(0, 0, 0); STAGE_B1(0, 0, 0);
    STAGE_A1(0, 1, 0); STAGE_B1(0, 1, 0);
    STAGE_A1(1, 0, 1); STAGE_B1(1, 0, 1);
    asm volatile("s_waitcnt vmcnt(8)" ::: "memory");
    __builtin_amdgcn_s_barrier();
    __builtin_amdgcn_sched_barrier(0);

    for (int t = 0; t < NT1; ++t) {
        const int bufp = t & 1, nbuf = bufp ^ 1;
        const u16* baseA0 = &LA[bufp][0][0][0];
        const u16* baseA1 = &LA[bufp][1][0][0];
        const u16* baseB0 = &LB[bufp][0][0][0];
        const u16* baseB1 = &LB[bufp][1][0][0];
        bf8 aF[4], bF[4];

        // ---- phase 0: (qi=0, ks=0) ----
#pragma unroll
        for (int j = 0; j < 4; ++j) bF[j] = *reinterpret_cast<const bf8*>(baseB0 + bOff[j]);
#pragma unroll
        for (int ii = 0; ii < 4; ++ii) aF[ii] = *reinterpret_cast<const bf8*>(baseA0 + aOff[ii]);
        if (t + 1 < NT1) STAGE_A1(t + 1, 1, nbuf);
        __builtin_amdgcn_s_barrier();
        asm volatile("s_waitcnt lgkmcnt(0)" ::: "memory");
        __builtin_amdgcn_sched_barrier(0);
        __builtin_amdgcn_s_setprio(1);
#pragma unroll
        for (int ii = 0; ii < 4; ++ii)
#pragma unroll
            for (int j = 0; j < 4; ++j)
                acc[ii][j] = __builtin_amdgcn_mfma_f32_16x16x32_bf16(aF[ii], bF[j], acc[ii][j], 0, 0, 0);
        __builtin_amdgcn_s_setprio(0);
        __builtin_amdgcn_s_barrier();
        __builtin_amdgcn_sched_barrier(0);

        // ---- phase 1: (qi=1, ks=0)  [bF reused] ----
#pragma unroll
        for (int ii = 0; ii < 4; ++ii) aF[ii] = *reinterpret_cast<const bf8*>(baseA0 + aOff[4 + ii]);
        if (t + 1 < NT1) STAGE_B1(t + 1, 1, nbuf);
        __builtin_amdgcn_s_barrier();
        asm volatile("s_waitcnt lgkmcnt(0)" ::: "memory");
        __builtin_amdgcn_sched_barrier(0);
        __builtin_amdgcn_s_setprio(1);
#pragma unroll
        for (int ii = 0; ii < 4; ++ii)
#pragma unroll
            for (int j = 0; j < 4; ++j)
                acc[4 + ii][j] = __builtin_amdgcn_mfma_f32_16x16x32_bf16(aF[ii], bF[j], acc[4 + ii][j], 0, 0, 0);
        __builtin_amdgcn_s_setprio(0);
        if (t < NT1 - 2) asm volatile("s_waitcnt vmcnt(8)" ::: "memory");
        else             asm volatile("s_waitcnt vmcnt(0)" ::: "memory");
        __builtin_amdgcn_s_barrier();
        __builtin_amdgcn_sched_barrier(0);

        // ---- phase 2: (qi=0, ks=1) ----
#pragma unroll
        for (int j = 0; j < 4; ++j) bF[j] = *reinterpret_cast<const bf8*>(baseB1 + bOff[j]);
#pragma unroll
        for (int ii = 0; ii < 4; ++ii) aF[ii] = *reinterpret_cast<const bf8*>(baseA1 + aOff[ii]);
        if (t + 2 < NT1) STAGE_A1(t + 2, 0, bufp);
        __builtin_amdgcn_s_barrier();
        asm volatile("s_waitcnt lgkmcnt(0)" ::: "memory");
        __builtin_amdgcn_sched_barrier(0);
        __builtin_amdgcn_s_setprio(1);
#pragma unroll
        for (int ii = 0; ii < 4; ++ii)
#pragma unroll
            for (int j = 0; j < 4; ++j)
                acc[ii][j] = __builtin_amdgcn_mfma_f32_16x16x32_bf16(aF[ii], bF[j], acc[ii][j], 0, 0, 0);
        __builtin_amdgcn_s_setprio(0);
        __builtin_amdgcn_s_barrier();
        __builtin_amdgcn_sched_barrier(0);

        // ---- phase 3: (qi=1, ks=1)  [bF reused] ----
#pragma unroll
        for (int ii = 0; ii < 4; ++ii) aF[ii] = *reinterpret_cast<const bf8*>(baseA1 + aOff[4 + ii]);
        if (t + 2 < NT1) STAGE_B1(t + 2, 0, bufp);
        __builtin_amdgcn_s_barrier();
        asm volatile("s_waitcnt lgkmcnt(0)" ::: "memory");
        __builtin_amdgcn_sched_barrier(0);
        __builtin_amdgcn_s_setprio(1);
#pragma unroll
        for (int ii = 0; ii < 4; ++ii)
#pragma unroll
            for (int j = 0; j < 4; ++j)
                acc[4 + ii][j] = __builtin_amdgcn_mfma_f32_16x16x32_bf16(aF[ii], bF[j], acc[4 + ii][j], 0, 0, 0);
        __builtin_amdgcn_s_setprio(0);
        if (t < NT1 - 2) asm volatile("s_waitcnt vmcnt(8)" ::: "memory");
        else             asm volatile("s_waitcnt vmcnt(0)" ::: "memory");
        __builtin_amdgcn_s_barrier();
        __builtin_amdgcn_sched_barrier(0);
    }
#undef STAGE_A1
#undef STAGE_B1

    // epilogue: store bf16 h' to hbuf[b][m][o] (o fast)
#pragma unroll
    for (int j = 0; j < 4; ++j) {
        int m = m0 + wc * 64 + j * 16 + (l & 15);
        size_t rowbase = (size_t)(b * M_ + m) * O1_;
#pragma unroll
        for (int i = 0; i < 8; ++i) {
            int orow = o0 + wr * 128 + i * 16 + (l >> 4) * 4;
            ushort4 pk;
            pk.x = f2bf(acc[i][j].x);
            pk.y = f2bf(acc[i][j].y);
            pk.z = f2bf(acc[i][j].z);
            pk.w = f2bf(acc[i][j].w);
            *reinterpret_cast<ushort4*>(&hbuf[rowbase + orow]) = pk;
        }
    }
}

// ---------------- per-channel sum / sumsq over h' (R6 version) ----------------
__global__ __launch_bounds__(256) void k_stats(const u16* __restrict__ hbuf, float* __restrict__ stats) {
    const int t = threadIdx.x;
    const size_t row0 = (size_t)blockIdx.x * 256;
    float s0 = 0.f, q0 = 0.f, s1 = 0.f, q1 = 0.f;
    for (int r = 0; r < 256; ++r) {
        const u16* p = hbuf + (row0 + r) * O1_;
        float v0 = bf2f(p[t]);
        float v1 = bf2f(p[t + 256]);
        s0 += v0; q0 += v0 * v0;
        s1 += v1; q1 += v1 * v1;
    }
    atomicAdd(&stats[t], s0);
    atomicAdd(&stats[O1_ + t], q0);
    atomicAdd(&stats[t + 256], s1);
    atomicAdd(&stats[O1_ + t + 256], q1);
}

__global__ void k_finalize_ac(const float* __restrict__ stats, const float* __restrict__ g1,
                              const float* __restrict__ bt1, float* __restrict__ ac) {
    int o = blockIdx.x * 256 + threadIdx.x;
    if (o >= O1_) return;
    const float inv = 1.0f / ((float)B_ * (float)M_);
    float mean = stats[o] * inv;
    float var  = stats[O1_ + o] * inv - mean * mean;
    var = fmaxf(var, 0.0f);
    float a = g1[o] * rsqrtf(var + 1e-5f);
    ac[o] = a;
    ac[O1_ + o] = bt1[o] - mean * a;   // b1 cancels: shift = bt1 - a*mean(h')
}

// ---------------- CSR build: count -> scan -> fill ----------------
__global__ void k_count_int(const int* __restrict__ idx, int* __restrict__ cnt) {
    int i = blockIdx.x * 256 + threadIdx.x;
    if (i < B_ * M_) atomicAdd(&cnt[(i >> 13) * N_ + idx[i]], 1);
}

__global__ __launch_bounds__(1024) void k_scan(const int* __restrict__ cnt, int* __restrict__ offs,
                                               int* __restrict__ fill) {
    __shared__ int wsum[1024];
    const int b = blockIdx.x;
    const int t = threadIdx.x;
    const int base = b * N_;
    int v[8]; int s = 0;
#pragma unroll
    for (int k = 0; k < 8; ++k) { v[k] = cnt[base + t * 8 + k]; s += v[k]; }
    wsum[t] = s;
    __syncthreads();
    for (int off = 1; off < 1024; off <<= 1) {
        int add = (t >= off) ? wsum[t - off] : 0;
        __syncthreads();
        wsum[t] += add;
        __syncthreads();
    }
    int run = (t > 0) ? wsum[t - 1] : 0;
#pragma unroll
    for (int k = 0; k < 8; ++k) {
        offs[base + t * 8 + k] = run;
        fill[base + t * 8 + k] = run;
        run += v[k];
    }
}

__global__ void k_fill(const int* __restrict__ idx, int* __restrict__ fill, int* __restrict__ mlist) {
    int i = blockIdx.x * 256 + threadIdx.x;
    if (i < B_ * M_) {
        int b = i >> 13, m = i & (M_ - 1);
        int pos = atomicAdd(&fill[b * N_ + idx[i]], 1);
        mlist[(size_t)b * M_ + pos] = m;
    }
}

// ---------------- GEMM2: up[b][m][d] = W2 @ relu(a*h'+c) + b2 (BN+ReLU fused into B-staging) ----------------
__global__ __launch_bounds__(256) void k_gemm2(const u16* __restrict__ W2b,
                                               const u16* __restrict__ hbuf,
                                               const float* __restrict__ ac,
                                               const float* __restrict__ b2,
                                               u16* __restrict__ up) {
    __shared__ u16 At[128 * 32];
    __shared__ u16 Bt[128 * 32];
    __shared__ float acs[1024];    // [0,512) scale a, [512,1024) shift c
    const int b  = blockIdx.z;
    const int d0 = blockIdx.y * 128;
    const int m0 = blockIdx.x * 128;
    const int tid = threadIdx.x;
    const int w = tid >> 6, l = tid & 63;
    const int lr = l >> 2, lc = (l & 3) * 8;

    acs[tid]       = ac[tid];
    acs[tid + 256] = ac[tid + 256];
    acs[tid + 512] = ac[tid + 512];
    acs[tid + 768] = ac[tid + 768];

    const u16* pA[2]; const u16* pB[2];
#pragma unroll
    for (int t = 0; t < 2; ++t) {
        int row = t * 64 + w * 16 + lr;
        pA[t] = W2b + (size_t)(d0 + row) * K2_ + lc;
        int m  = m0 + row;
        pB[t] = hbuf + (size_t)(b * M_ + m) * O1_ + lc;
    }
    const int wr = w >> 1, wc = w & 1;
    f4 acc[4][4];
#pragma unroll
    for (int i = 0; i < 4; ++i)
#pragma unroll
        for (int j = 0; j < 4; ++j) acc[i][j] = {0.f, 0.f, 0.f, 0.f};

    const int aoff = (wr * 64 + (l & 15)) * 32 + (l >> 4) * 8;
    const int boff = (wc * 64 + (l & 15)) * 32 + (l >> 4) * 8;
    const int bdst = (w * 16 + lr) * 32 + lc;   // +t*64*32 per chunk

    __syncthreads();   // acs visible before first transform

    for (int kk = 0; kk < 16; ++kk) {
        const int o = kk * 32 + lc;
        f4 A0 = *reinterpret_cast<const f4*>(&acs[o]);
        f4 A1 = *reinterpret_cast<const f4*>(&acs[o + 4]);
        f4 C0 = *reinterpret_cast<const f4*>(&acs[512 + o]);
        f4 C1 = *reinterpret_cast<const f4*>(&acs[512 + o + 4]);
#pragma unroll
        for (int t = 0; t < 2; ++t) {
            gl_lds16(pA[t] + kk * 32, At + (t * 64 + w * 16) * 32);
            const ushort4* ps = reinterpret_cast<const ushort4*>(pB[t] + kk * 32);
            ushort4 v0 = ps[0], v1 = ps[1];
            union { ushort4 u4[2]; bf8 v8; } pk;
            pk.u4[0].x = f2bf(fmaxf(bf2f(v0.x) * A0.x + C0.x, 0.0f));
            pk.u4[0].y = f2bf(fmaxf(bf2f(v0.y) * A0.y + C0.y, 0.0f));
            pk.u4[0].z = f2bf(fmaxf(bf2f(v0.z) * A0.z + C0.z, 0.0f));
            pk.u4[0].w = f2bf(fmaxf(bf2f(v0.w) * A0.w + C0.w, 0.0f));
            pk.u4[1].x = f2bf(fmaxf(bf2f(v1.x) * A1.x + C1.x, 0.0f));
            pk.u4[1].y = f2bf(fmaxf(bf2f(v1.y) * A1.y + C1.y, 0.0f));
            pk.u4[1].z = f2bf(fmaxf(bf2f(v1.z) * A1.z + C1.z, 0.0f));
            pk.u4[1].w = f2bf(fmaxf(bf2f(v1.w) * A1.w + C1.w, 0.0f));
            *reinterpret_cast<bf8*>(&Bt[t * 64 * 32 + bdst]) = pk.v8;
        }
        __syncthreads();
        bf8 aF[4], bF[4];
#pragma unroll
        for (int i = 0; i < 4; ++i) aF[i] = *reinterpret_cast<const bf8*>(&At[aoff + i * 16 * 32]);
#pragma unroll
        for (int j = 0; j < 4; ++j) bF[j] = *reinterpret_cast<const bf8*>(&Bt[boff + j * 16 * 32]);
#pragma unroll
        for (int i = 0; i < 4; ++i)
#pragma unroll
            for (int j = 0; j < 4; ++j)
                acc[i][j] = __builtin_amdgcn_mfma_f32_16x16x32_bf16(aF[i], bF[j], acc[i][j], 0, 0, 0);
        __syncthreads();
    }

    // epilogue: +b2, plain bf16 stores to up[b][m][d]
#pragma unroll
    for (int j = 0; j < 4; ++j) {
        int m = m0 + wc * 64 + j * 16 + (l & 15);
        size_t rowbase = (size_t)(b * M_ + m) * D_;
#pragma unroll
        for (int i = 0; i < 4; ++i) {
            int d = d0 + wr * 64 + i * 16 + (l >> 4) * 4;
            ushort4 pk;
            pk.x = f2bf(acc[i][j].x + b2[d + 0]);
            pk.y = f2bf(acc[i][j].y + b2[d + 1]);
            pk.z = f2bf(acc[i][j].z + b2[d + 2]);
            pk.w = f2bf(acc[i][j].w + b2[d + 3]);
            *reinterpret_cast<ushort4*>(&up[rowbase + d]) = pk;
        }
    }
}

// ---------------- out[b][d][n] = ldesc + mean_{m in list(n)} up[b][m][d] ----------------
__global__ __launch_bounds__(256) void k_reduce_finalize(const float* __restrict__ ldesc,
                                                         const u16* __restrict__ up,
                                                         const int* __restrict__ cnt,
                                                         const int* __restrict__ offs,
                                                         const int* __restrict__ mlist,
                                                         float* __restrict__ out) {
    __shared__ float lds[32][257];
    const int b  = blockIdx.z;
    const int n0 = blockIdx.x * 32;
    const int tx = threadIdx.x, ty = threadIdx.y;   // (32,8)
#pragma unroll
    for (int i = 0; i < 4; ++i) {
        int nl = ty + i * 8;
        int n  = n0 + nl;
        int c   = cnt[b * N_ + n];
        int off = offs[b * N_ + n];
        float inv = 1.0f / (float)max(c, 1);
        float acc[8] = {0.f, 0.f, 0.f, 0.f, 0.f, 0.f, 0.f, 0.f};
        for (int e = 0; e < c; ++e) {
            int m = mlist[(size_t)b * M_ + off + e];
            const ushort4* row = reinterpret_cast<const ushort4*>(up + (size_t)(b * M_ + m) * D_ + tx * 8);
            ushort4 aa = row[0], bb = row[1];
            acc[0] += bf2f(aa.x); acc[1] += bf2f(aa.y); acc[2] += bf2f(aa.z); acc[3] += bf2f(aa.w);
            acc[4] += bf2f(bb.x); acc[5] += bf2f(bb.y); acc[6] += bf2f(bb.z); acc[7] += bf2f(bb.w);
        }
#pragma unroll
        for (int k = 0; k < 8; ++k) lds[nl][tx * 8 + k] = acc[k] * inv;
    }
    __syncthreads();
#pragma unroll
    for (int i = 0; i < 32; ++i) {
        int d = ty + i * 8;
        size_t o2 = (size_t)(b * D_ + d) * N_ + n0 + tx;
        out[o2] = ldesc[o2] + lds[tx][d];
    }
}

__global__ void k_marker(float* out, float v) { out[0] = v; }

extern "C" void kernel_launch(void* const* d_in, const int* in_sizes, int n_in,
                              void* d_out, int out_size, void* d_ws, size_t ws_size,
                              hipStream_t stream) {
    const float* ldesc0 = (const float*)d_in[0];
    const float* ldesc1 = (const float*)d_in[1];
    const float* le0    = (const float*)d_in[2];
    const float* le1    = (const float*)d_in[3];
    const int*   idx0   = (const int*)d_in[4];
    const int*   idx1   = (const int*)d_in[5];
    const float* W1     = (const float*)d_in[6];
    const float* g1     = (const float*)d_in[8];
    const float* bt1    = (const float*)d_in[9];
    const float* W2     = (const float*)d_in[10];
    const float* b2     = (const float*)d_in[11];
    float* out = (float*)d_out;

    char* ws = (char*)d_ws;
    const size_t oTld   = 0;                            // bf16 [B][N][D] 33.5MB; aliased by `up` after gemm1
    const size_t oTle   = 33554432;                     // bf16 [B][M][D] 33.5MB; aliased by CSR after gemm1
    const size_t oH     = 67108864;                     // bf16 [B][M][O1] 67MB
    const size_t oW1b   = 134217728;                    // 786,432 B
    const size_t oW2b   = oW1b + 786432;                // 262,144 B
    const size_t oStats = oW2b + 262144;                // 4,096 B
    const size_t oAC    = oStats + 4096;                // 4,096 B
    const size_t NEED   = oAC + 4096;
    if (ws_size < NEED) {
        k_marker<<<1, 1, 0, stream>>>(out, 1000.0f + (float)(ws_size >> 20));
        return;
    }
    u16*   Tld   = (u16*)(ws + oTld);
    u16*   up    = (u16*)(ws + oTld);                   // alias (Tld dead after gemm1)
    u16*   Tle   = (u16*)(ws + oTle);
    int*   cnt   = (int*)(ws + oTle);                   // CSR aliases Tle (dead after gemm1)
    int*   offs  = (int*)(ws + oTle + 262144);
    int*   fill  = (int*)(ws + oTle + 524288);
    int*   mlist = (int*)(ws + oTle + 786432);
    u16*   hbuf  = (u16*)(ws + oH);
    u16*   W1b   = (u16*)(ws + oW1b);
    u16*   W2b   = (u16*)(ws + oW2b);
    float* stats = (float*)(ws + oStats);
    float* ac    = (float*)(ws + oAC);

    k_convert_w<<<2048, 256, 0, stream>>>(W1, W2, W1b, W2b);

    const dim3 tb(32, 8);
    for (int s = 0; s < 2; ++s) {
        const float* ld  = s ? ldesc1 : ldesc0;
        const float* le  = s ? le1 : le0;
        const int*   idx = s ? idx1 : idx0;
        float* outp = out + (size_t)s * B_ * D_ * N_;

        k_transpose_bf16<<<dim3(N_ / 32, D_ / 32, B_), tb, 0, stream>>>(ld, Tld, D_, N_);
        k_transpose_bf16<<<dim3(M_ / 32, D_ / 32, B_), tb, 0, stream>>>(le, Tle, D_, M_);
        k_gemm1<<<dim3(M_ / 256, O1_ / 256, B_), 512, 0, stream>>>(W1b, Tld, Tle, idx, hbuf);
        // BN stats (streaming) + coefficients
        hipMemsetAsync(stats, 0, 4096, stream);
        k_stats<<<256, 256, 0, stream>>>(hbuf, stats);
        k_finalize_ac<<<2, 256, 0, stream>>>(stats, g1, bt1, ac);
        // CSR of idx (Tle region is dead now)
        hipMemsetAsync(cnt, 0, (size_t)B_ * N_ * 4, stream);
        k_count_int<<<B_ * M_ / 256, 256, 0, stream>>>(idx, cnt);
        k_scan<<<B_, 1024, 0, stream>>>(cnt, offs, fill);
        k_fill<<<B_ * M_ / 256, 256, 0, stream>>>(idx, fill, mlist);
        // GEMM2 (fused BN+ReLU) -> up (Tld region is dead now), then gather-mean + residual
        k_gemm2<<<dim3(M_ / 128, D_ / 128, B_), 256, 0, stream>>>(W2b, hbuf, ac, b2, up);
        k_reduce_finalize<<<dim3(N_ / 32, 1, B_), tb, 0, stream>>>(ld, up, cnt, offs, mlist, outp);
    }
}

// Round 10
// 412.864 us; speedup vs baseline: 1.3054x; 1.0981x over previous
//
#include <hip/hip_runtime.h>
#include <hip/hip_bf16.h>

#define B_  8
#define D_  256
#define N_  8192
#define M_  8192
#define O1_ 512     // 2D
#define K1_ 768     // 3D
#define K2_ 512     // 2D

typedef unsigned short u16;
typedef __attribute__((ext_vector_type(8))) short bf8;   // 8 bf16 = 4 VGPRs
typedef __attribute__((ext_vector_type(4))) float f4;

static __device__ __forceinline__ float bf2f(u16 u) {
    unsigned v = ((unsigned)u) << 16;
    return __uint_as_float(v);
}
static __device__ __forceinline__ u16 f2bf(float f) {
    __hip_bfloat16 h = __float2bfloat16(f);
    return *reinterpret_cast<u16*>(&h);
}
// async global->LDS, 16B per lane; LDS dest = wave-uniform base + lane*16
static __device__ __forceinline__ void gl_lds16(const u16* g, u16* l) {
    __builtin_amdgcn_global_load_lds((const __attribute__((address_space(1))) void*)g,
                                     (__attribute__((address_space(3))) void*)l, 16, 0, 0);
}
// byte-offset swizzle within a 64B LDS row (bits 4,5 from row bits 1,2) — 0 conflicts (R8-verified)
static __device__ __forceinline__ int swz64(int r) {
    return (((r >> 1) & 1) << 4) | (((r >> 2) & 1) << 5);
}

// ---------------- transpose f32 [B][D][8192] -> bf16 [B][8192][D], all 4 tensors in one launch ----------------
__global__ __launch_bounds__(256) void k_transpose_all(const float* __restrict__ s0, const float* __restrict__ s1,
                                                       const float* __restrict__ s2, const float* __restrict__ s3,
                                                       u16* __restrict__ dA, u16* __restrict__ dB) {
    __shared__ float t[32][33];
    const int z = blockIdx.z;
    const int sel = z >> 3, b = z & 7;        // sel: 0=ldesc0 1=ldesc1 2=le0 3=le1
    const float* src = (sel == 0) ? s0 : (sel == 1) ? s1 : (sel == 2) ? s2 : s3;
    u16* dst = ((sel < 2) ? dA : dB) + (size_t)(sel & 1) * B_ * N_ * D_;
    const int c0 = blockIdx.x * 32, r0 = blockIdx.y * 32;
    const int tx = threadIdx.x, ty = threadIdx.y;     // block (32,8)
    const float* s = src + (size_t)b * D_ * N_;
    u16* d = dst + (size_t)b * N_ * D_;
#pragma unroll
    for (int i = 0; i < 4; ++i) {
        int r = r0 + ty + i * 8;
        t[ty + i * 8][tx] = s[(size_t)r * N_ + (c0 + tx)];
    }
    __syncthreads();
#pragma unroll
    for (int i = 0; i < 4; ++i) {
        int c = c0 + ty + i * 8;
        d[(size_t)c * D_ + (r0 + tx)] = f2bf(t[tx][ty + i * 8]);
    }
}

// ---------------- weights f32 -> bf16 ----------------
__global__ __launch_bounds__(256) void k_convert_w(const float* __restrict__ W1, const float* __restrict__ W2,
                                                   u16* __restrict__ W1b, u16* __restrict__ W2b) {
    int i = blockIdx.x * 256 + threadIdx.x;
    const int n1 = O1_ * K1_;
    const int n2 = D_ * K2_;
    if (i < n1) W1b[i] = f2bf(W1[i]);
    int j = i - n1;
    if (j >= 0 && j < n2) W2b[j] = f2bf(W2[j]);
}

// ---------------- GEMM1: 256x256 tile, 8 waves, BK=64 (2 ks-planes), 8-phase dbuf, counted vmcnt ----------------
// both sides in one launch: z = side*8 + b
#define NT1 12    // K1/64
__global__ __launch_bounds__(512, 2) void k_gemm1(const u16* __restrict__ W1b,
                                                  const u16* __restrict__ Tld2,
                                                  const u16* __restrict__ Tle2,
                                                  const int* __restrict__ idx0,
                                                  const int* __restrict__ idx1,
                                                  u16* __restrict__ hbuf2) {
    __shared__ u16 LA[2][2][256][32];   // [buf][ks][row o][32 u16 = 64B] : 64 KB
    __shared__ u16 LB[2][2][256][32];   // [buf][ks][row m][...]          : 64 KB
    const int z  = blockIdx.z;
    const int side = z >> 3, b = z & 7;
    const u16* Tld = Tld2 + (size_t)side * B_ * N_ * D_;
    const u16* Tle = Tle2 + (size_t)side * B_ * N_ * D_;
    const int* idx = side ? idx1 : idx0;
    u16* hbuf = hbuf2 + (size_t)side * B_ * M_ * O1_;
    const int o0 = blockIdx.y * 256;
    const int m0 = blockIdx.x * 256;
    const int tid = threadIdx.x;
    const int w = tid >> 6, l = tid & 63;
    const int wr = w >> 2;      // o half: 128 rows
    const int wc = w & 3;       // m quarter: 64 rows

    const int srow   = tid >> 2;          // 0..127
    const int schunk = (tid & 3) * 16;    // byte offset in 64B row

    int na[2], nb[2], mm[2];
    const u16* aS[2];
    int bcolu[2];
#pragma unroll
    for (int j = 0; j < 2; ++j) {
        int r = j * 128 + srow;
        int m = m0 + r;
        mm[j] = m;
        na[j] = idx[b * M_ + m];
        nb[j] = idx[b * M_ + (m ^ 1)];
        int swu = (schunk ^ swz64(r)) >> 1;          // pre-swizzled source chunk (u16)
        aS[j]   = W1b + (size_t)(o0 + r) * K1_ + swu;
        bcolu[j] = swu;
    }

    int aOff[8], bOff[4];
#pragma unroll
    for (int i = 0; i < 8; ++i) {
        int r = wr * 128 + i * 16 + (l & 15);
        aOff[i] = r * 32 + ((((l >> 4) * 16) ^ swz64(r)) >> 1);
    }
#pragma unroll
    for (int j = 0; j < 4; ++j) {
        int r = wc * 64 + j * 16 + (l & 15);
        bOff[j] = r * 32 + ((((l >> 4) * 16) ^ swz64(r)) >> 1);
    }

#define STAGE_A1(kt, ks, buf)                                                        \
    {                                                                                \
        _Pragma("unroll")                                                            \
        for (int j = 0; j < 2; ++j)                                                  \
            gl_lds16(aS[j] + (kt) * 64 + (ks) * 32, &LA[buf][ks][j * 128][0] + tid * 8); \
    }
#define STAGE_B1(kt, ks, buf)                                                        \
    {                                                                                \
        const int seg = (kt) >> 2;                                                   \
        const int cb  = ((kt) & 3) * 64 + (ks) * 32;                                 \
        _Pragma("unroll")                                                            \
        for (int j = 0; j < 2; ++j) {                                                \
            const u16* s;                                                            \
            if (seg == 0)      s = Tld + (size_t)(b * N_ + na[j]) * D_ + cb + bcolu[j]; \
            else if (seg == 1) s = Tld + (size_t)(b * N_ + nb[j]) * D_ + cb + bcolu[j]; \
            else               s = Tle + (size_t)(b * M_ + mm[j]) * D_ + cb + bcolu[j]; \
            gl_lds16(s, &LB[buf][ks][j * 128][0] + tid * 8);                         \
        }                                                                            \
    }

    f4 acc[8][4];
#pragma unroll
    for (int i = 0; i < 8; ++i)
#pragma unroll
        for (int j = 0; j < 4; ++j) acc[i][j] = {0.f, 0.f, 0.f, 0.f};

    STAGE_A1(0, 0, 0); STAGE_B1(0, 0, 0);
    STAGE_A1(0, 1, 0); STAGE_B1(0, 1, 0);
    STAGE_A1(1, 0, 1); STAGE_B1(1, 0, 1);
    asm volatile("s_waitcnt vmcnt(8)" ::: "memory");
    __builtin_amdgcn_s_barrier();
    __builtin_amdgcn_sched_barrier(0);

    for (int t = 0; t < NT1; ++t) {
        const int bufp = t & 1, nbuf = bufp ^ 1;
        const u16* baseA0 = &LA[bufp][0][0][0];
        const u16* baseA1 = &LA[bufp][1][0][0];
        const u16* baseB0 = &LB[bufp][0][0][0];
        const u16* baseB1 = &LB[bufp][1][0][0];
        bf8 aF[4], bF[4];

        // ---- phase 0: (qi=0, ks=0) ----
#pragma unroll
        for (int j = 0; j < 4; ++j) bF[j] = *reinterpret_cast<const bf8*>(baseB0 + bOff[j]);
#pragma unroll
        for (int ii = 0; ii < 4; ++ii) aF[ii] = *reinterpret_cast<const bf8*>(baseA0 + aOff[ii]);
        if (t + 1 < NT1) STAGE_A1(t + 1, 1, nbuf);
        __builtin_amdgcn_s_barrier();
        asm volatile("s_waitcnt lgkmcnt(0)" ::: "memory");
        __builtin_amdgcn_sched_barrier(0);
        __builtin_amdgcn_s_setprio(1);
#pragma unroll
        for (int ii = 0; ii < 4; ++ii)
#pragma unroll
            for (int j = 0; j < 4; ++j)
                acc[ii][j] = __builtin_amdgcn_mfma_f32_16x16x32_bf16(aF[ii], bF[j], acc[ii][j], 0, 0, 0);
        __builtin_amdgcn_s_setprio(0);
        __builtin_amdgcn_s_barrier();
        __builtin_amdgcn_sched_barrier(0);

        // ---- phase 1: (qi=1, ks=0)  [bF reused] ----
#pragma unroll
        for (int ii = 0; ii < 4; ++ii) aF[ii] = *reinterpret_cast<const bf8*>(baseA0 + aOff[4 + ii]);
        if (t + 1 < NT1) STAGE_B1(t + 1, 1, nbuf);
        __builtin_amdgcn_s_barrier();
        asm volatile("s_waitcnt lgkmcnt(0)" ::: "memory");
        __builtin_amdgcn_sched_barrier(0);
        __builtin_amdgcn_s_setprio(1);
#pragma unroll
        for (int ii = 0; ii < 4; ++ii)
#pragma unroll
            for (int j = 0; j < 4; ++j)
                acc[4 + ii][j] = __builtin_amdgcn_mfma_f32_16x16x32_bf16(aF[ii], bF[j], acc[4 + ii][j], 0, 0, 0);
        __builtin_amdgcn_s_setprio(0);
        if (t < NT1 - 2) asm volatile("s_waitcnt vmcnt(8)" ::: "memory");
        else             asm volatile("s_waitcnt vmcnt(0)" ::: "memory");
        __builtin_amdgcn_s_barrier();
        __builtin_amdgcn_sched_barrier(0);

        // ---- phase 2: (qi=0, ks=1) ----
#pragma unroll
        for (int j = 0; j < 4; ++j) bF[j] = *reinterpret_cast<const bf8*>(baseB1 + bOff[j]);
#pragma unroll
        for (int ii = 0; ii < 4; ++ii) aF[ii] = *reinterpret_cast<const bf8*>(baseA1 + aOff[ii]);
        if (t + 2 < NT1) STAGE_A1(t + 2, 0, bufp);
        __builtin_amdgcn_s_barrier();
        asm volatile("s_waitcnt lgkmcnt(0)" ::: "memory");
        __builtin_amdgcn_sched_barrier(0);
        __builtin_amdgcn_s_setprio(1);
#pragma unroll
        for (int ii = 0; ii < 4; ++ii)
#pragma unroll
            for (int j = 0; j < 4; ++j)
                acc[ii][j] = __builtin_amdgcn_mfma_f32_16x16x32_bf16(aF[ii], bF[j], acc[ii][j], 0, 0, 0);
        __builtin_amdgcn_s_setprio(0);
        __builtin_amdgcn_s_barrier();
        __builtin_amdgcn_sched_barrier(0);

        // ---- phase 3: (qi=1, ks=1)  [bF reused] ----
#pragma unroll
        for (int ii = 0; ii < 4; ++ii) aF[ii] = *reinterpret_cast<const bf8*>(baseA1 + aOff[4 + ii]);
        if (t + 2 < NT1) STAGE_B1(t + 2, 0, bufp);
        __builtin_amdgcn_s_barrier();
        asm volatile("s_waitcnt lgkmcnt(0)" ::: "memory");
        __builtin_amdgcn_sched_barrier(0);
        __builtin_amdgcn_s_setprio(1);
#pragma unroll
        for (int ii = 0; ii < 4; ++ii)
#pragma unroll
            for (int j = 0; j < 4; ++j)
                acc[4 + ii][j] = __builtin_amdgcn_mfma_f32_16x16x32_bf16(aF[ii], bF[j], acc[4 + ii][j], 0, 0, 0);
        __builtin_amdgcn_s_setprio(0);
        if (t < NT1 - 2) asm volatile("s_waitcnt vmcnt(8)" ::: "memory");
        else             asm volatile("s_waitcnt vmcnt(0)" ::: "memory");
        __builtin_amdgcn_s_barrier();
        __builtin_amdgcn_sched_barrier(0);
    }
#undef STAGE_A1
#undef STAGE_B1

    // epilogue: store bf16 h' to hbuf[b][m][o] (o fast)
#pragma unroll
    for (int j = 0; j < 4; ++j) {
        int m = m0 + wc * 64 + j * 16 + (l & 15);
        size_t rowbase = (size_t)(b * M_ + m) * O1_;
#pragma unroll
        for (int i = 0; i < 8; ++i) {
            int orow = o0 + wr * 128 + i * 16 + (l >> 4) * 4;
            ushort4 pk;
            pk.x = f2bf(acc[i][j].x);
            pk.y = f2bf(acc[i][j].y);
            pk.z = f2bf(acc[i][j].z);
            pk.w = f2bf(acc[i][j].w);
            *reinterpret_cast<ushort4*>(&hbuf[rowbase + orow]) = pk;
        }
    }
}

// ---------------- per-channel sum / sumsq over h', both sides ----------------
__global__ __launch_bounds__(256) void k_stats(const u16* __restrict__ hbuf2, float* __restrict__ stats) {
    const int side = blockIdx.x >> 8;
    const int blk  = blockIdx.x & 255;
    const u16* hb = hbuf2 + (size_t)side * B_ * M_ * O1_;
    float* st = stats + side * 1024;
    const int t = threadIdx.x;
    const size_t row0 = (size_t)blk * 256;
    float s0 = 0.f, q0 = 0.f, s1 = 0.f, q1 = 0.f;
    for (int r = 0; r < 256; ++r) {
        const u16* p = hb + (row0 + r) * O1_;
        float v0 = bf2f(p[t]);
        float v1 = bf2f(p[t + 256]);
        s0 += v0; q0 += v0 * v0;
        s1 += v1; q1 += v1 * v1;
    }
    atomicAdd(&st[t], s0);
    atomicAdd(&st[O1_ + t], q0);
    atomicAdd(&st[t + 256], s1);
    atomicAdd(&st[O1_ + t + 256], q1);
}

__global__ void k_finalize_ac(const float* __restrict__ stats, const float* __restrict__ g1,
                              const float* __restrict__ bt1, float* __restrict__ ac) {
    int i = blockIdx.x * 256 + threadIdx.x;   // 0..1023
    if (i >= 1024) return;
    int side = i >> 9, o = i & 511;
    const float* st = stats + side * 1024;
    const float inv = 1.0f / ((float)B_ * (float)M_);
    float mean = st[o] * inv;
    float var  = st[O1_ + o] * inv - mean * mean;
    var = fmaxf(var, 0.0f);
    float a = g1[o] * rsqrtf(var + 1e-5f);
    ac[side * 1024 + o] = a;
    ac[side * 1024 + O1_ + o] = bt1[o] - mean * a;   // b1 cancels: shift = bt1 - a*mean(h')
}

// ---------------- CSR build (both sides): count -> scan -> fill ----------------
__global__ void k_count_int(const int* __restrict__ idx0, const int* __restrict__ idx1, int* __restrict__ cnt2) {
    int i = blockIdx.x * 256 + threadIdx.x;       // 0 .. 2*B*M
    if (i < 2 * B_ * M_) {
        int side = i >> 16, j = i & 65535;
        const int* idx = side ? idx1 : idx0;
        atomicAdd(&cnt2[side * B_ * N_ + (j >> 13) * N_ + idx[j]], 1);
    }
}

__global__ __launch_bounds__(1024) void k_scan(const int* __restrict__ cnt2, int* __restrict__ offs2,
                                               int* __restrict__ fill2) {
    __shared__ int wsum[1024];
    const int base = blockIdx.x * N_;    // blockIdx.x = side*8+b
    const int t = threadIdx.x;
    int v[8]; int s = 0;
#pragma unroll
    for (int k = 0; k < 8; ++k) { v[k] = cnt2[base + t * 8 + k]; s += v[k]; }
    wsum[t] = s;
    __syncthreads();
    for (int off = 1; off < 1024; off <<= 1) {
        int add = (t >= off) ? wsum[t - off] : 0;
        __syncthreads();
        wsum[t] += add;
        __syncthreads();
    }
    int run = (t > 0) ? wsum[t - 1] : 0;
#pragma unroll
    for (int k = 0; k < 8; ++k) {
        offs2[base + t * 8 + k] = run;
        fill2[base + t * 8 + k] = run;
        run += v[k];
    }
}

__global__ void k_fill(const int* __restrict__ idx0, const int* __restrict__ idx1,
                       int* __restrict__ fill2, int* __restrict__ mlist2) {
    int i = blockIdx.x * 256 + threadIdx.x;
    if (i < 2 * B_ * M_) {
        int side = i >> 16, j = i & 65535;
        const int* idx = side ? idx1 : idx0;
        int b = j >> 13, m = j & (M_ - 1);
        int pos = atomicAdd(&fill2[side * B_ * N_ + b * N_ + idx[j]], 1);
        mlist2[(size_t)side * B_ * M_ + b * M_ + pos] = m;
    }
}

// ---------------- GEMM2: up[b][m][d] = W2 @ relu(a*h'+c) + b2, both sides ----------------
__global__ __launch_bounds__(256) void k_gemm2(const u16* __restrict__ W2b,
                                               const u16* __restrict__ hbuf2,
                                               const float* __restrict__ ac,
                                               const float* __restrict__ b2,
                                               u16* __restrict__ up2) {
    __shared__ u16 At[128 * 32];
    __shared__ u16 Bt[128 * 32];
    __shared__ float acs[1024];    // [0,512) scale a, [512,1024) shift c
    const int z = blockIdx.z;
    const int side = z >> 3, b = z & 7;
    const u16* hbuf = hbuf2 + (size_t)side * B_ * M_ * O1_;
    u16* up = up2 + (size_t)side * B_ * M_ * D_;
    const float* acp = ac + side * 1024;
    const int d0 = blockIdx.y * 128;
    const int m0 = blockIdx.x * 128;
    const int tid = threadIdx.x;
    const int w = tid >> 6, l = tid & 63;
    const int lr = l >> 2, lc = (l & 3) * 8;

    acs[tid]       = acp[tid];
    acs[tid + 256] = acp[tid + 256];
    acs[tid + 512] = acp[tid + 512];
    acs[tid + 768] = acp[tid + 768];

    const u16* pA[2]; const u16* pB[2];
#pragma unroll
    for (int t = 0; t < 2; ++t) {
        int row = t * 64 + w * 16 + lr;
        pA[t] = W2b + (size_t)(d0 + row) * K2_ + lc;
        int m  = m0 + row;
        pB[t] = hbuf + (size_t)(b * M_ + m) * O1_ + lc;
    }
    const int wr = w >> 1, wc = w & 1;
    f4 acc[4][4];
#pragma unroll
    for (int i = 0; i < 4; ++i)
#pragma unroll
        for (int j = 0; j < 4; ++j) acc[i][j] = {0.f, 0.f, 0.f, 0.f};

    const int aoff = (wr * 64 + (l & 15)) * 32 + (l >> 4) * 8;
    const int boff = (wc * 64 + (l & 15)) * 32 + (l >> 4) * 8;
    const int bdst = (w * 16 + lr) * 32 + lc;   // +t*64*32 per chunk

    __syncthreads();   // acs visible before first transform

    for (int kk = 0; kk < 16; ++kk) {
        const int o = kk * 32 + lc;
        f4 A0 = *reinterpret_cast<const f4*>(&acs[o]);
        f4 A1 = *reinterpret_cast<const f4*>(&acs[o + 4]);
        f4 C0 = *reinterpret_cast<const f4*>(&acs[512 + o]);
        f4 C1 = *reinterpret_cast<const f4*>(&acs[512 + o + 4]);
#pragma unroll
        for (int t = 0; t < 2; ++t) {
            gl_lds16(pA[t] + kk * 32, At + (t * 64 + w * 16) * 32);
            const ushort4* ps = reinterpret_cast<const ushort4*>(pB[t] + kk * 32);
            ushort4 v0 = ps[0], v1 = ps[1];
            union { ushort4 u4[2]; bf8 v8; } pk;
            pk.u4[0].x = f2bf(fmaxf(bf2f(v0.x) * A0.x + C0.x, 0.0f));
            pk.u4[0].y = f2bf(fmaxf(bf2f(v0.y) * A0.y + C0.y, 0.0f));
            pk.u4[0].z = f2bf(fmaxf(bf2f(v0.z) * A0.z + C0.z, 0.0f));
            pk.u4[0].w = f2bf(fmaxf(bf2f(v0.w) * A0.w + C0.w, 0.0f));
            pk.u4[1].x = f2bf(fmaxf(bf2f(v1.x) * A1.x + C1.x, 0.0f));
            pk.u4[1].y = f2bf(fmaxf(bf2f(v1.y) * A1.y + C1.y, 0.0f));
            pk.u4[1].z = f2bf(fmaxf(bf2f(v1.z) * A1.z + C1.z, 0.0f));
            pk.u4[1].w = f2bf(fmaxf(bf2f(v1.w) * A1.w + C1.w, 0.0f));
            *reinterpret_cast<bf8*>(&Bt[t * 64 * 32 + bdst]) = pk.v8;
        }
        __syncthreads();
        bf8 aF[4], bF[4];
#pragma unroll
        for (int i = 0; i < 4; ++i) aF[i] = *reinterpret_cast<const bf8*>(&At[aoff + i * 16 * 32]);
#pragma unroll
        for (int j = 0; j < 4; ++j) bF[j] = *reinterpret_cast<const bf8*>(&Bt[boff + j * 16 * 32]);
#pragma unroll
        for (int i = 0; i < 4; ++i)
#pragma unroll
            for (int j = 0; j < 4; ++j)
                acc[i][j] = __builtin_amdgcn_mfma_f32_16x16x32_bf16(aF[i], bF[j], acc[i][j], 0, 0, 0);
        __syncthreads();
    }

    // epilogue: +b2, plain bf16 stores to up[b][m][d]
#pragma unroll
    for (int j = 0; j < 4; ++j) {
        int m = m0 + wc * 64 + j * 16 + (l & 15);
        size_t rowbase = (size_t)(b * M_ + m) * D_;
#pragma unroll
        for (int i = 0; i < 4; ++i) {
            int d = d0 + wr * 64 + i * 16 + (l >> 4) * 4;
            ushort4 pk;
            pk.x = f2bf(acc[i][j].x + b2[d + 0]);
            pk.y = f2bf(acc[i][j].y + b2[d + 1]);
            pk.z = f2bf(acc[i][j].z + b2[d + 2]);
            pk.w = f2bf(acc[i][j].w + b2[d + 3]);
            *reinterpret_cast<ushort4*>(&up[rowbase + d]) = pk;
        }
    }
}

// ---------------- out[b][d][n] = ldesc + mean_{m in list(n)} up[b][m][d], both sides ----------------
__global__ __launch_bounds__(256) void k_reduce_finalize(const float* __restrict__ ldesc0,
                                                         const float* __restrict__ ldesc1,
                                                         const u16* __restrict__ up2,
                                                         const int* __restrict__ cnt2,
                                                         const int* __restrict__ offs2,
                                                         const int* __restrict__ mlist2,
                                                         float* __restrict__ out) {
    __shared__ float lds[32][257];
    const int z = blockIdx.z;
    const int side = z >> 3, b = z & 7;
    const float* ldesc = side ? ldesc1 : ldesc0;
    const u16* up = up2 + (size_t)side * B_ * M_ * D_;
    const int* cnt  = cnt2  + side * B_ * N_;
    const int* offs = offs2 + side * B_ * N_;
    const int* mlist = mlist2 + (size_t)side * B_ * M_;
    float* outp = out + (size_t)side * B_ * D_ * N_;
    const int n0 = blockIdx.x * 32;
    const int tx = threadIdx.x, ty = threadIdx.y;   // (32,8)
#pragma unroll
    for (int i = 0; i < 4; ++i) {
        int nl = ty + i * 8;
        int n  = n0 + nl;
        int c   = cnt[b * N_ + n];
        int off = offs[b * N_ + n];
        float inv = 1.0f / (float)max(c, 1);
        float acc[8] = {0.f, 0.f, 0.f, 0.f, 0.f, 0.f, 0.f, 0.f};
        for (int e = 0; e < c; ++e) {
            int m = mlist[(size_t)b * M_ + off + e];
            const ushort4* row = reinterpret_cast<const ushort4*>(up + (size_t)(b * M_ + m) * D_ + tx * 8);
            ushort4 aa = row[0], bb = row[1];
            acc[0] += bf2f(aa.x); acc[1] += bf2f(aa.y); acc[2] += bf2f(aa.z); acc[3] += bf2f(aa.w);
            acc[4] += bf2f(bb.x); acc[5] += bf2f(bb.y); acc[6] += bf2f(bb.z); acc[7] += bf2f(bb.w);
        }
#pragma unroll
        for (int k = 0; k < 8; ++k) lds[nl][tx * 8 + k] = acc[k] * inv;
    }
    __syncthreads();
#pragma unroll
    for (int i = 0; i < 32; ++i) {
        int d = ty + i * 8;
        size_t o2 = (size_t)(b * D_ + d) * N_ + n0 + tx;
        outp[o2] = ldesc[o2] + lds[tx][d];
    }
}

__global__ void k_marker(float* out, float v) { out[0] = v; }

extern "C" void kernel_launch(void* const* d_in, const int* in_sizes, int n_in,
                              void* d_out, int out_size, void* d_ws, size_t ws_size,
                              hipStream_t stream) {
    const float* ldesc0 = (const float*)d_in[0];
    const float* ldesc1 = (const float*)d_in[1];
    const float* le0    = (const float*)d_in[2];
    const float* le1    = (const float*)d_in[3];
    const int*   idx0   = (const int*)d_in[4];
    const int*   idx1   = (const int*)d_in[5];
    const float* W1     = (const float*)d_in[6];
    const float* g1     = (const float*)d_in[8];
    const float* bt1    = (const float*)d_in[9];
    const float* W2     = (const float*)d_in[10];
    const float* b2     = (const float*)d_in[11];
    float* out = (float*)d_out;

    char* ws = (char*)d_ws;
    const size_t SIDE_BND = (size_t)B_ * N_ * D_ * 2;   // 33,554,432 B (bf16 [B][N][D])
    const size_t oTld2  = 0;                            // 2 sides: 67,108,864 (aliased by up2 later)
    const size_t oTle2  = 2 * SIDE_BND;                 // 2 sides: 67,108,864 (aliased by CSR later)
    const size_t oH2    = 4 * SIDE_BND;                 // 2 sides bf16 [B][M][O1]: 134,217,728
    const size_t oW1b   = oH2 + (size_t)2 * B_ * M_ * O1_ * 2;   // 268,435,456
    const size_t oW2b   = oW1b + 786432;
    const size_t oStats = oW2b + 262144;
    const size_t oAC    = oStats + 8192;
    const size_t NEED   = oAC + 8192;
    if (ws_size < NEED) {
        k_marker<<<1, 1, 0, stream>>>(out, 1000.0f + (float)(ws_size >> 20));
        return;
    }
    u16*   Tld2  = (u16*)(ws + oTld2);
    u16*   up2   = (u16*)(ws + oTld2);                  // alias (Tld dead after gemm1)
    u16*   Tle2  = (u16*)(ws + oTle2);
    int*   cnt2  = (int*)(ws + oTle2);                  // CSR aliases Tle2 (dead after gemm1)
    int*   offs2 = (int*)(ws + oTle2 + 524288);
    int*   fill2 = (int*)(ws + oTle2 + 1048576);
    int*   mlist2= (int*)(ws + oTle2 + 1572864);
    u16*   hbuf2 = (u16*)(ws + oH2);
    u16*   W1b   = (u16*)(ws + oW1b);
    u16*   W2b   = (u16*)(ws + oW2b);
    float* stats = (float*)(ws + oStats);
    float* ac    = (float*)(ws + oAC);

    k_convert_w<<<2048, 256, 0, stream>>>(W1, W2, W1b, W2b);

    const dim3 tb(32, 8);
    // 1) all 4 transposes in one launch
    k_transpose_all<<<dim3(N_ / 32, D_ / 32, 32), tb, 0, stream>>>(ldesc0, ldesc1, le0, le1, Tld2, Tle2);
    // 2) gemm1 both sides
    k_gemm1<<<dim3(M_ / 256, O1_ / 256, 16), 512, 0, stream>>>(W1b, Tld2, Tle2, idx0, idx1, hbuf2);
    // 3) BN stats + coefficients (both sides)
    hipMemsetAsync(stats, 0, 8192, stream);
    k_stats<<<512, 256, 0, stream>>>(hbuf2, stats);
    k_finalize_ac<<<4, 256, 0, stream>>>(stats, g1, bt1, ac);
    // 4) CSR both sides (Tle2 region dead now)
    hipMemsetAsync(cnt2, 0, (size_t)2 * B_ * N_ * 4, stream);
    k_count_int<<<2 * B_ * M_ / 256, 256, 0, stream>>>(idx0, idx1, cnt2);
    k_scan<<<16, 1024, 0, stream>>>(cnt2, offs2, fill2);
    k_fill<<<2 * B_ * M_ / 256, 256, 0, stream>>>(idx0, idx1, fill2, mlist2);
    // 5) gemm2 both sides (Tld2 region dead now) + gather-mean + residual
    k_gemm2<<<dim3(M_ / 128, D_ / 128, 16), 256, 0, stream>>>(W2b, hbuf2, ac, b2, up2);
    k_reduce_finalize<<<dim3(N_ / 32, 1, 16), tb, 0, stream>>>(ldesc0, ldesc1, up2, cnt2, offs2, mlist2, out);
}